// Round 19
// baseline (218.991 us; speedup 1.0000x reference)
//
#include <hip/hip_runtime.h>
#include <hip/hip_fp8.h>

// ---------------------------------------------------------------------------
// GraphSAGE 2-layer encoder, MI355X.
//   out = leaky( mean_{j->i}(h_j) @ Wl + b + h_i @ Wr ), slope 0.5, x2 layers
// R19: agg widened to 16 rows in flight (VGPR ~60, still <=64 so full
// occupancy). Everything else frozen from R18 (all-fp8 operands, fixed-CAP
// buckets, atomic-free parallel CSR chain, unified single-barrier GEMM).
// ---------------------------------------------------------------------------

typedef __attribute__((ext_vector_type(8))) short bf16x8;
typedef __attribute__((ext_vector_type(4))) float f32x4;

__device__ __forceinline__ short f2bf(float f) {
    union { float f; unsigned u; } x; x.f = f;
    unsigned r = x.u + 0x7fffu + ((x.u >> 16) & 1u);
    return (short)(r >> 16);
}
__device__ __forceinline__ unsigned char f2fp8(float f) {
    __hip_fp8_e4m3 q(f);
    return (unsigned char)q.__x;
}
__device__ __forceinline__ float fp82f(unsigned char b) {
    __hip_fp8_e4m3 q; q.__x = (__hip_fp8_storage_t)b;
    return (float)q;
}

// -------------------- bkhist + prep (fused, independent block ranges) ------
// histT layout: histT[b * 128 + c], b < 512 buckets, c < 128 chunks.

__global__ __launch_bounds__(512) void bkhist_prep_kernel(
    const int* __restrict__ ei, int* __restrict__ histT,
    int E, int NBK, int NCH, int CH,
    const float* __restrict__ x,
    unsigned char* __restrict__ xq, float* __restrict__ xcopy,
    const float* __restrict__ Wl0, const float* __restrict__ Wr0,
    const float* __restrict__ Wl1, const float* __restrict__ Wr1,
    short* __restrict__ B1T, short* __restrict__ B2T, int total8) {
    if ((int)blockIdx.x < NCH) {
        __shared__ int h[512];
        int c = blockIdx.x;
        int base_e = c * CH;
        int nloc = E - base_e;
        if (nloc > CH) nloc = CH;
        h[threadIdx.x] = 0;
        __syncthreads();
        for (int t = threadIdx.x; t < nloc; t += 512)
            atomicAdd(&h[ei[E + base_e + t] >> 7], 1);
        __syncthreads();
        if ((int)threadIdx.x < NBK) histT[threadIdx.x * 128 + c] = h[threadIdx.x];
    } else {
        int gid = ((int)blockIdx.x - NCH) * 512 + threadIdx.x;
        if (gid < total8) {
            const float* p = x + (size_t)gid * 8;
            float4 v0 = *reinterpret_cast<const float4*>(p);
            float4 v1 = *reinterpret_cast<const float4*>(p + 4);
            uchar4 q0, q1;
            q0.x = f2fp8(v0.x); q0.y = f2fp8(v0.y); q0.z = f2fp8(v0.z); q0.w = f2fp8(v0.w);
            q1.x = f2fp8(v1.x); q1.y = f2fp8(v1.y); q1.z = f2fp8(v1.z); q1.w = f2fp8(v1.w);
            *reinterpret_cast<uchar4*>(xq + (size_t)gid * 8) = q0;
            *reinterpret_cast<uchar4*>(xq + (size_t)gid * 8 + 4) = q1;
            *reinterpret_cast<float4*>(xcopy + (size_t)gid * 8) = v0;
            *reinterpret_cast<float4*>(xcopy + (size_t)gid * 8 + 4) = v1;
        } else {
            int idx = gid - total8;            // 0 .. 262143
            if (idx < 262144) {
                int sel = idx >> 17;
                int j = idx & 131071;
                int n = j >> 9;
                int k = j & 511;
                const float* Wl = sel ? Wl1 : Wl0;
                const float* Wr = sel ? Wr1 : Wr0;
                float v = (k < 256) ? Wl[k * 256 + n] : Wr[(k - 256) * 256 + n];
                (sel ? B2T : B1T)[j] = f2bf(v);
            }
        }
    }
}

// -------------------- scanA: one wave per bucket over chunks ---------------
__global__ __launch_bounds__(256) void scanA_kernel(
    int* __restrict__ histT, int* __restrict__ bktot, int NBK, int NCH) {
    int waveid = blockIdx.x * 4 + (threadIdx.x >> 6);
    int lane = threadIdx.x & 63;
    if (waveid >= NBK) return;
    int b = waveid;
    int v0 = (lane < NCH) ? histT[b * 128 + lane] : 0;
    int v1 = (64 + lane < NCH) ? histT[b * 128 + 64 + lane] : 0;
    int s0 = v0;
    #pragma unroll
    for (int d = 1; d < 64; d <<= 1) {
        int t = __shfl_up(s0, d, 64);
        if (lane >= d) s0 += t;
    }
    int t0 = __shfl(s0, 63, 64);
    int s1 = v1;
    #pragma unroll
    for (int d = 1; d < 64; d <<= 1) {
        int t = __shfl_up(s1, d, 64);
        if (lane >= d) s1 += t;
    }
    s1 += t0;
    if (lane < NCH) histT[b * 128 + lane] = s0 - v0;
    if (64 + lane < NCH) histT[b * 128 + 64 + lane] = s1 - v1;
    if (lane == 63) bktot[b] = __shfl(s1, 63, 64);
}

// -------------------- binA: scatter packed pairs (no global atomics) -------
// Bucket b's region = [b*CAP, b*CAP + bktot[b]).  pack=(dst&127)<<25 | src.
__global__ __launch_bounds__(512) void binA_kernel(
    const int* __restrict__ ei, const int* __restrict__ histT,
    unsigned* __restrict__ pairs, int E, int NBK, int CH, int CAP) {
    __shared__ int pos[512];
    int c = blockIdx.x;
    if ((int)threadIdx.x < NBK)
        pos[threadIdx.x] = histT[threadIdx.x * 128 + c] + threadIdx.x * CAP;
    __syncthreads();
    int base_e = c * CH;
    int nloc = E - base_e;
    if (nloc > CH) nloc = CH;
    for (int t = threadIdx.x; t < nloc; t += 512) {
        int dst = ei[E + base_e + t];
        int src = ei[base_e + t];
        int p = atomicAdd(&pos[dst >> 7], 1);
        pairs[p] = ((unsigned)(dst & 127) << 25) | (unsigned)src;
    }
}

// -------------------- binB: per-node offs/oend/invdeg + csr scatter --------
__global__ __launch_bounds__(256) void binB_kernel(
    const unsigned* __restrict__ pairs, const int* __restrict__ bktot,
    int* __restrict__ offs, int* __restrict__ oend, float* __restrict__ invdeg,
    int* __restrict__ csr, int NBK, int N, int CAP) {
    __shared__ int cnt[128];
    __shared__ int cur[128];
    int b = blockIdx.x;
    int t = threadIdx.x;
    if (t < 128) cnt[t] = 0;
    __syncthreads();
    int beg = b * CAP;
    int end = beg + bktot[b];
    for (int i = beg + t; i < end; i += 256)
        atomicAdd(&cnt[pairs[i] >> 25], 1);
    __syncthreads();
    if (t < 64) {
        int c0 = cnt[2 * t], c1 = cnt[2 * t + 1];
        int s = c0 + c1;
        int incl = s;
        #pragma unroll
        for (int d = 1; d < 64; d <<= 1) {
            int x = __shfl_up(incl, d, 64);
            if (t >= d) incl += x;
        }
        int excl = incl - s;
        cur[2 * t] = beg + excl;
        cur[2 * t + 1] = beg + excl + c0;
    }
    __syncthreads();
    if (t < 128) {
        int node = (b << 7) + t;
        if (node < N) {
            offs[node] = cur[t];
            oend[node] = cur[t] + cnt[t];
            invdeg[node] = 1.0f / (float)(cnt[t] > 0 ? cnt[t] : 1);
        }
    }
    __syncthreads();
    for (int i = beg + t; i < end; i += 256) {
        unsigned p = pairs[i];
        int pos = atomicAdd(&cur[p >> 25], 1);
        csr[pos] = (int)(p & 0x1FFFFFFu);
    }
}

// -------------------- mean aggregation (fp8 gather, fp8 out) ---------------
// One wave per node; lane t owns elements [4t,4t+4) (4B fp8/lane).
// 16 independent row loads in flight (VGPR ~60 <= 64: full occupancy).
__global__ __launch_bounds__(256) void agg_kernel(
    const unsigned char* __restrict__ feat,
    const int* __restrict__ offs, const int* __restrict__ oend,
    const int* __restrict__ csr, const float* __restrict__ invdeg,
    unsigned char* __restrict__ outp, int N) {
    int wave = threadIdx.x >> 6;
    int lane = threadIdx.x & 63;
    int node = blockIdx.x * 4 + wave;
    if (node >= N) return;
    int beg = offs[node];
    int end = oend[node];
    int c = lane * 4;

    float a[4][4];
    #pragma unroll
    for (int u = 0; u < 4; ++u)
        #pragma unroll
        for (int k = 0; k < 4; ++k) a[u][k] = 0.f;

    int deg = end - beg;
    int n16 = deg & ~15;
    for (int t = 0; t < n16; t += 16) {
        int s[16];
        #pragma unroll
        for (int j = 0; j < 16; ++j) s[j] = csr[beg + t + j];
        unsigned u[16];
        #pragma unroll
        for (int j = 0; j < 16; ++j)
            u[j] = *reinterpret_cast<const unsigned*>(
                feat + (size_t)s[j] * 256 + c);
        #pragma unroll
        for (int j = 0; j < 16; ++j) {
            #pragma unroll
            for (int k = 0; k < 4; ++k)
                a[j & 3][k] += fp82f((u[j] >> (8 * k)) & 0xff);
        }
    }
    int rem = beg + n16;
    int left = end - rem;
    int n8 = left & ~7;
    for (int t = 0; t < n8; t += 8) {
        int s[8];
        #pragma unroll
        for (int j = 0; j < 8; ++j) s[j] = csr[rem + t + j];
        unsigned u[8];
        #pragma unroll
        for (int j = 0; j < 8; ++j)
            u[j] = *reinterpret_cast<const unsigned*>(
                feat + (size_t)s[j] * 256 + c);
        #pragma unroll
        for (int j = 0; j < 8; ++j) {
            #pragma unroll
            for (int k = 0; k < 4; ++k)
                a[j & 3][k] += fp82f((u[j] >> (8 * k)) & 0xff);
        }
    }
    for (int e = rem + n8; e < end; ++e) {
        int s = csr[e];
        unsigned u = *reinterpret_cast<const unsigned*>(
            feat + (size_t)s * 256 + c);
        #pragma unroll
        for (int k = 0; k < 4; ++k) a[0][k] += fp82f((u >> (8 * k)) & 0xff);
    }
    float inv = invdeg[node];
    uchar4 o;
    o.x = f2fp8((a[0][0] + a[1][0] + a[2][0] + a[3][0]) * inv);
    o.y = f2fp8((a[0][1] + a[1][1] + a[2][1] + a[3][1]) * inv);
    o.z = f2fp8((a[0][2] + a[1][2] + a[2][2] + a[3][2]) * inv);
    o.w = f2fp8((a[0][3] + a[1][3] + a[2][3] + a[3][3]) * inv);
    *reinterpret_cast<uchar4*>(&outp[(size_t)node * 256 + c]) = o;
}

// -------------------- fused GEMM + bias + leaky (all-fp8 operands) ---------
// (R18 design, frozen.) C[M][256] = leaky([AL|AR][M][512] @ B + bias).
// Persistent 512 blocks, 16 waves, wave owns 16 cols; breg = B col-slice.
// 32-row tiles, split dbuf LDS; both A-halves fp8 reg-staged (uint2 ->
// exact fp8->bf16 -> swizzled ds_write_b128). Single-barrier pipeline:
// STAGE(next) -> MFMA(cur) -> vmcnt(0) -> WRITE(next) -> stores ->
// lgkmcnt(0) -> s_barrier. Swizzle: X[r][j ^ ((r&15)<<3)] per half.
// C/D: lane l, reg r -> row (l>>4)*4+r, col l&15. OOB rows clamp to M-1.
template <int OUT_MODE>   // 0: fp8 h0q out, 1: f32 d_out
__global__ __launch_bounds__(1024, 4) void gemm_kernel(
    const unsigned char* __restrict__ ALq, const unsigned char* __restrict__ ARq,
    const short* __restrict__ BT, const float* __restrict__ bias,
    float* __restrict__ Cout, unsigned char* __restrict__ Cq,
    int M, int ntiles) {
    __shared__ short ldsAL[2][32 * 256];
    __shared__ short ldsAR[2][32 * 256];
    int wave = threadIdx.x >> 6;        // 0..15
    int lane = threadIdx.x & 63;
    int l16 = lane & 15;
    int lhi = lane >> 4;
    int c0 = wave * 16;
    int rsub = lane >> 5;               // 0/1: which of the wave's 2 rows
    int jcol = (lane & 31) * 8;         // element column within row

    bf16x8 breg[16];
    #pragma unroll
    for (int kk = 0; kk < 16; ++kk)
        breg[kk] = *reinterpret_cast<const bf16x8*>(
            &BT[(size_t)(c0 + l16) * 512 + kk * 32 + lhi * 8]);
    float bc = bias[c0 + l16];

    uint2 nqL, nqR;                     // staged fp8 row fragments

    auto STAGE = [&](int tt) {
        int r = 2 * wave + rsub;
        int grow = tt * 32 + r;
        if (grow >= M) grow = M - 1;
        int off = jcol ^ ((r & 15) << 3);
        nqL = *reinterpret_cast<const uint2*>(ALq + (size_t)grow * 256 + off);
        nqR = *reinterpret_cast<const uint2*>(ARq + (size_t)grow * 256 + off);
    };
    auto WRITE = [&](int buf) {         // dequant + swizzled LDS writes
        int r = 2 * wave + rsub;
        bf16x8 wl, wr;
        #pragma unroll
        for (int k = 0; k < 4; ++k) {
            wl[k]     = f2bf(fp82f((nqL.x >> (8 * k)) & 0xff));
            wl[4 + k] = f2bf(fp82f((nqL.y >> (8 * k)) & 0xff));
            wr[k]     = f2bf(fp82f((nqR.x >> (8 * k)) & 0xff));
            wr[4 + k] = f2bf(fp82f((nqR.y >> (8 * k)) & 0xff));
        }
        *reinterpret_cast<bf16x8*>(&ldsAL[buf][r * 256 + jcol]) = wl;
        *reinterpret_cast<bf16x8*>(&ldsAR[buf][r * 256 + jcol]) = wr;
    };

    int t = blockIdx.x;
    int stride = gridDim.x;
    if (t >= ntiles) return;

    // prologue: fill buffer 0 (also drains breg loads)
    STAGE(t);
    asm volatile("s_waitcnt vmcnt(0)" ::: "memory");
    WRITE(0);
    asm volatile("s_waitcnt lgkmcnt(0)" ::: "memory");
    __builtin_amdgcn_s_barrier();
    __builtin_amdgcn_sched_barrier(0);

    int buf = 0;
    for (; t < ntiles; t += stride) {
        int tn = t + stride;
        bool havenext = (tn < ntiles);
        if (havenext) STAGE(tn);            // loads fly under this tile

        int row0 = t * 32;
        f32x4 acc[2];
        acc[0] = (f32x4){0.f, 0.f, 0.f, 0.f};
        acc[1] = (f32x4){0.f, 0.f, 0.f, 0.f};

        #pragma unroll
        for (int kk = 0; kk < 16; ++kk) {
            const short* lb = (kk < 8) ? &ldsAL[buf][0] : &ldsAR[buf][0];
            int kb = (kk & 7) * 32 + lhi * 8;
            int swz0 = (l16 & 15) << 3;     // same for row l16 and 16+l16
            bf16x8 a0 = *reinterpret_cast<const bf16x8*>(
                &lb[l16 * 256 + (kb ^ swz0)]);
            bf16x8 a1 = *reinterpret_cast<const bf16x8*>(
                &lb[(16 + l16) * 256 + (kb ^ swz0)]);
            acc[0] = __builtin_amdgcn_mfma_f32_16x16x32_bf16(
                a0, breg[kk], acc[0], 0, 0, 0);
            acc[1] = __builtin_amdgcn_mfma_f32_16x16x32_bf16(
                a1, breg[kk], acc[1], 0, 0, 0);
        }

        // nq(next) in regs, prev stores done -- covered by MFMA phase.
        asm volatile("s_waitcnt vmcnt(0)" ::: "memory");
        if (havenext) WRITE(buf ^ 1);

        #pragma unroll
        for (int mt = 0; mt < 2; ++mt) {
            #pragma unroll
            for (int r = 0; r < 4; ++r) {
                int grow = row0 + mt * 16 + lhi * 4 + r;
                if (grow >= M) grow = M - 1;   // clamp (value-correct)
                int gcol = c0 + l16;
                float v = acc[mt][r] + bc;
                v = (v >= 0.f) ? v : 0.5f * v;
                if (OUT_MODE == 0) {
                    Cq[(size_t)grow * 256 + gcol] = f2fp8(v);
                } else {
                    Cout[(size_t)grow * 256 + gcol] = v;
                }
            }
        }
        asm volatile("s_waitcnt lgkmcnt(0)" ::: "memory");
        __builtin_amdgcn_s_barrier();
        __builtin_amdgcn_sched_barrier(0);
        buf ^= 1;
    }
}

// -------------------- launch --------------------

extern "C" void kernel_launch(void* const* d_in, const int* in_sizes, int n_in,
                              void* d_out, int out_size, void* d_ws, size_t ws_size,
                              hipStream_t stream) {
    const float* x   = (const float*)d_in[0];
    const int*   ei  = (const int*)d_in[1];   // int64 in ref -> int32 from harness
    const float* Wl0 = (const float*)d_in[2];
    const float* bl0 = (const float*)d_in[3];
    const float* Wr0 = (const float*)d_in[4];
    const float* Wl1 = (const float*)d_in[5];
    const float* bl1 = (const float*)d_in[6];
    const float* Wr1 = (const float*)d_in[7];

    const int N = in_sizes[0] / 256;
    const int E = in_sizes[1] / 2;
    const int NBK = (N + 127) / 128;               // <= 512
    int CH = 8192;
    while ((E + CH - 1) / CH > 128) CH <<= 1;      // NCH <= 128
    const int NCH = (E + CH - 1) / CH;
    int CAP = 1;
    while (CAP < 4 * (E / NBK + 1)) CAP <<= 1;     // bucket capacity, pow2

    char* ws = (char*)d_ws;
    size_t o = 0;
    auto alloc = [&](size_t bytes) {
        size_t p = o;
        o = (o + bytes + 255) & ~(size_t)255;
        return p;
    };
    int*   offs   = (int*)  (ws + alloc((size_t)N * 4));
    int*   oendv  = (int*)  (ws + alloc((size_t)N * 4));
    float* invdeg = (float*)(ws + alloc((size_t)N * 4));
    int*   histT  = (int*)  (ws + alloc((size_t)512 * 128 * 4));
    int*   bktot  = (int*)  (ws + alloc(512 * 4));
    unsigned* pairs = (unsigned*)(ws + alloc((size_t)NBK * CAP * 4));
    int*   csr    = (int*)  (ws + alloc((size_t)NBK * CAP * 4));
    unsigned char* meanb = (unsigned char*)(ws + alloc((size_t)N * 256));
    unsigned char* xq    = (unsigned char*)(ws + alloc((size_t)N * 256));
    unsigned char* h0q   = (unsigned char*)(ws + alloc((size_t)N * 256));
    short* B1T    = (short*)(ws + alloc(262144));
    short* B2T    = (short*)(ws + alloc(262144));

    int total8 = N * 32;
    int prep_blocks = (total8 + 262144 + 511) / 512;
    bkhist_prep_kernel<<<NCH + prep_blocks, 512, 0, stream>>>(
        ei, histT, E, NBK, NCH, CH,
        x, xq, (float*)d_out + (size_t)N * 256,
        Wl0, Wr0, Wl1, Wr1, B1T, B2T, total8);
    scanA_kernel<<<(NBK + 3) / 4, 256, 0, stream>>>(histT, bktot, NBK, NCH);
    binA_kernel<<<NCH, 512, 0, stream>>>(ei, histT, pairs, E, NBK, CH, CAP);
    binB_kernel<<<NBK, 256, 0, stream>>>(pairs, bktot, offs, oendv, invdeg,
                                         csr, NBK, N, CAP);

    int ab = (N + 3) / 4;
    int ntiles = (N + 31) / 32;
    int gblocks = 512;
    // layer 0
    agg_kernel<<<ab, 256, 0, stream>>>(xq, offs, oendv, csr, invdeg, meanb, N);
    gemm_kernel<0><<<gblocks, 1024, 0, stream>>>(
        meanb, xq, B1T, bl0, nullptr, h0q, N, ntiles);
    // layer 1
    agg_kernel<<<ab, 256, 0, stream>>>(h0q, offs, oendv, csr, invdeg, meanb, N);
    gemm_kernel<1><<<gblocks, 1024, 0, stream>>>(
        meanb, h0q, B2T, bl1, (float*)d_out, nullptr, N, ntiles);
}

// Round 20
// 206.288 us; speedup vs baseline: 1.0616x; 1.0616x over previous
//
#include <hip/hip_runtime.h>
#include <hip/hip_fp8.h>

// ---------------------------------------------------------------------------
// GraphSAGE 2-layer encoder, MI355X.
//   out = leaky( mean_{j->i}(h_j) @ Wl + b + h_i @ Wr ), slope 0.5, x2 layers
// R20 = exact revert to R18 (best measured: 205.9us, absmax 0.0625).
// R19's 16-row agg regressed (deg~16 -> tail-dominated + VGPR>64 cliff;
// same failure as R11). 8-row agg is twice-confirmed optimal.
// Components (all best-of-lineage):
//   - all-fp8 activations (xq/meanb/h0q); bf16 only inside LDS for MFMA
//   - atomic-free CSR: private hists + wave-scan + fixed-CAP binning
//   - unified single-barrier GEMM: persistent 16-wave, both A-halves
//     reg-staged fp8 -> dequant -> swizzled ds_write; breg B col-slice
//   - prep (x->fp8 + x->d_out copy + B^T build) fused with histograms
// ---------------------------------------------------------------------------

typedef __attribute__((ext_vector_type(8))) short bf16x8;
typedef __attribute__((ext_vector_type(4))) float f32x4;

__device__ __forceinline__ short f2bf(float f) {
    union { float f; unsigned u; } x; x.f = f;
    unsigned r = x.u + 0x7fffu + ((x.u >> 16) & 1u);
    return (short)(r >> 16);
}
__device__ __forceinline__ unsigned char f2fp8(float f) {
    __hip_fp8_e4m3 q(f);
    return (unsigned char)q.__x;
}
__device__ __forceinline__ float fp82f(unsigned char b) {
    __hip_fp8_e4m3 q; q.__x = (__hip_fp8_storage_t)b;
    return (float)q;
}

// -------------------- bkhist + prep (fused, independent block ranges) ------
// histT layout: histT[b * 128 + c], b < 512 buckets, c < 128 chunks.

__global__ __launch_bounds__(512) void bkhist_prep_kernel(
    const int* __restrict__ ei, int* __restrict__ histT,
    int E, int NBK, int NCH, int CH,
    const float* __restrict__ x,
    unsigned char* __restrict__ xq, float* __restrict__ xcopy,
    const float* __restrict__ Wl0, const float* __restrict__ Wr0,
    const float* __restrict__ Wl1, const float* __restrict__ Wr1,
    short* __restrict__ B1T, short* __restrict__ B2T, int total8) {
    if ((int)blockIdx.x < NCH) {
        __shared__ int h[512];
        int c = blockIdx.x;
        int base_e = c * CH;
        int nloc = E - base_e;
        if (nloc > CH) nloc = CH;
        h[threadIdx.x] = 0;
        __syncthreads();
        for (int t = threadIdx.x; t < nloc; t += 512)
            atomicAdd(&h[ei[E + base_e + t] >> 7], 1);
        __syncthreads();
        if ((int)threadIdx.x < NBK) histT[threadIdx.x * 128 + c] = h[threadIdx.x];
    } else {
        int gid = ((int)blockIdx.x - NCH) * 512 + threadIdx.x;
        if (gid < total8) {
            const float* p = x + (size_t)gid * 8;
            float4 v0 = *reinterpret_cast<const float4*>(p);
            float4 v1 = *reinterpret_cast<const float4*>(p + 4);
            uchar4 q0, q1;
            q0.x = f2fp8(v0.x); q0.y = f2fp8(v0.y); q0.z = f2fp8(v0.z); q0.w = f2fp8(v0.w);
            q1.x = f2fp8(v1.x); q1.y = f2fp8(v1.y); q1.z = f2fp8(v1.z); q1.w = f2fp8(v1.w);
            *reinterpret_cast<uchar4*>(xq + (size_t)gid * 8) = q0;
            *reinterpret_cast<uchar4*>(xq + (size_t)gid * 8 + 4) = q1;
            *reinterpret_cast<float4*>(xcopy + (size_t)gid * 8) = v0;
            *reinterpret_cast<float4*>(xcopy + (size_t)gid * 8 + 4) = v1;
        } else {
            int idx = gid - total8;            // 0 .. 262143
            if (idx < 262144) {
                int sel = idx >> 17;
                int j = idx & 131071;
                int n = j >> 9;
                int k = j & 511;
                const float* Wl = sel ? Wl1 : Wl0;
                const float* Wr = sel ? Wr1 : Wr0;
                float v = (k < 256) ? Wl[k * 256 + n] : Wr[(k - 256) * 256 + n];
                (sel ? B2T : B1T)[j] = f2bf(v);
            }
        }
    }
}

// -------------------- scanA: one wave per bucket over chunks ---------------
// histT[b][c] -> exclusive prefix within bucket b; bktot[b] = bucket total.
__global__ __launch_bounds__(256) void scanA_kernel(
    int* __restrict__ histT, int* __restrict__ bktot, int NBK, int NCH) {
    int waveid = blockIdx.x * 4 + (threadIdx.x >> 6);
    int lane = threadIdx.x & 63;
    if (waveid >= NBK) return;
    int b = waveid;
    int v0 = (lane < NCH) ? histT[b * 128 + lane] : 0;
    int v1 = (64 + lane < NCH) ? histT[b * 128 + 64 + lane] : 0;
    int s0 = v0;
    #pragma unroll
    for (int d = 1; d < 64; d <<= 1) {
        int t = __shfl_up(s0, d, 64);
        if (lane >= d) s0 += t;
    }
    int t0 = __shfl(s0, 63, 64);
    int s1 = v1;
    #pragma unroll
    for (int d = 1; d < 64; d <<= 1) {
        int t = __shfl_up(s1, d, 64);
        if (lane >= d) s1 += t;
    }
    s1 += t0;
    if (lane < NCH) histT[b * 128 + lane] = s0 - v0;
    if (64 + lane < NCH) histT[b * 128 + 64 + lane] = s1 - v1;
    if (lane == 63) bktot[b] = __shfl(s1, 63, 64);
}

// -------------------- binA: scatter packed pairs (no global atomics) -------
// Bucket b's region = [b*CAP, b*CAP + bktot[b]).  pack=(dst&127)<<25 | src.
__global__ __launch_bounds__(512) void binA_kernel(
    const int* __restrict__ ei, const int* __restrict__ histT,
    unsigned* __restrict__ pairs, int E, int NBK, int CH, int CAP) {
    __shared__ int pos[512];
    int c = blockIdx.x;
    if ((int)threadIdx.x < NBK)
        pos[threadIdx.x] = histT[threadIdx.x * 128 + c] + threadIdx.x * CAP;
    __syncthreads();
    int base_e = c * CH;
    int nloc = E - base_e;
    if (nloc > CH) nloc = CH;
    for (int t = threadIdx.x; t < nloc; t += 512) {
        int dst = ei[E + base_e + t];
        int src = ei[base_e + t];
        int p = atomicAdd(&pos[dst >> 7], 1);
        pairs[p] = ((unsigned)(dst & 127) << 25) | (unsigned)src;
    }
}

// -------------------- binB: per-node offs/oend/invdeg + csr scatter --------
__global__ __launch_bounds__(256) void binB_kernel(
    const unsigned* __restrict__ pairs, const int* __restrict__ bktot,
    int* __restrict__ offs, int* __restrict__ oend, float* __restrict__ invdeg,
    int* __restrict__ csr, int NBK, int N, int CAP) {
    __shared__ int cnt[128];
    __shared__ int cur[128];
    int b = blockIdx.x;
    int t = threadIdx.x;
    if (t < 128) cnt[t] = 0;
    __syncthreads();
    int beg = b * CAP;
    int end = beg + bktot[b];
    for (int i = beg + t; i < end; i += 256)
        atomicAdd(&cnt[pairs[i] >> 25], 1);
    __syncthreads();
    if (t < 64) {
        int c0 = cnt[2 * t], c1 = cnt[2 * t + 1];
        int s = c0 + c1;
        int incl = s;
        #pragma unroll
        for (int d = 1; d < 64; d <<= 1) {
            int x = __shfl_up(incl, d, 64);
            if (t >= d) incl += x;
        }
        int excl = incl - s;
        cur[2 * t] = beg + excl;
        cur[2 * t + 1] = beg + excl + c0;
    }
    __syncthreads();
    if (t < 128) {
        int node = (b << 7) + t;
        if (node < N) {
            offs[node] = cur[t];
            oend[node] = cur[t] + cnt[t];
            invdeg[node] = 1.0f / (float)(cnt[t] > 0 ? cnt[t] : 1);
        }
    }
    __syncthreads();
    for (int i = beg + t; i < end; i += 256) {
        unsigned p = pairs[i];
        int pos = atomicAdd(&cur[p >> 25], 1);
        csr[pos] = (int)(p & 0x1FFFFFFu);
    }
}

// -------------------- mean aggregation (fp8 gather, fp8 out) ---------------
// One wave per node; lane t owns elements [4t,4t+4) (4B fp8/lane).
// 8 independent row loads in flight (twice-confirmed optimum).
__global__ __launch_bounds__(256) void agg_kernel(
    const unsigned char* __restrict__ feat,
    const int* __restrict__ offs, const int* __restrict__ oend,
    const int* __restrict__ csr, const float* __restrict__ invdeg,
    unsigned char* __restrict__ outp, int N) {
    int wave = threadIdx.x >> 6;
    int lane = threadIdx.x & 63;
    int node = blockIdx.x * 4 + wave;
    if (node >= N) return;
    int beg = offs[node];
    int end = oend[node];
    int c = lane * 4;

    float a[4][4];
    #pragma unroll
    for (int u = 0; u < 4; ++u)
        #pragma unroll
        for (int k = 0; k < 4; ++k) a[u][k] = 0.f;

    int deg = end - beg;
    int n8 = deg & ~7;
    for (int t = 0; t < n8; t += 8) {
        int s0 = csr[beg + t];     int s1 = csr[beg + t + 1];
        int s2 = csr[beg + t + 2]; int s3 = csr[beg + t + 3];
        int s4 = csr[beg + t + 4]; int s5 = csr[beg + t + 5];
        int s6 = csr[beg + t + 6]; int s7 = csr[beg + t + 7];
        unsigned u0 = *reinterpret_cast<const unsigned*>(feat + (size_t)s0 * 256 + c);
        unsigned u1 = *reinterpret_cast<const unsigned*>(feat + (size_t)s1 * 256 + c);
        unsigned u2 = *reinterpret_cast<const unsigned*>(feat + (size_t)s2 * 256 + c);
        unsigned u3 = *reinterpret_cast<const unsigned*>(feat + (size_t)s3 * 256 + c);
        unsigned u4 = *reinterpret_cast<const unsigned*>(feat + (size_t)s4 * 256 + c);
        unsigned u5 = *reinterpret_cast<const unsigned*>(feat + (size_t)s5 * 256 + c);
        unsigned u6 = *reinterpret_cast<const unsigned*>(feat + (size_t)s6 * 256 + c);
        unsigned u7 = *reinterpret_cast<const unsigned*>(feat + (size_t)s7 * 256 + c);
        #pragma unroll
        for (int k = 0; k < 4; ++k) a[0][k] += fp82f((u0 >> (8 * k)) & 0xff);
        #pragma unroll
        for (int k = 0; k < 4; ++k) a[1][k] += fp82f((u1 >> (8 * k)) & 0xff);
        #pragma unroll
        for (int k = 0; k < 4; ++k) a[2][k] += fp82f((u2 >> (8 * k)) & 0xff);
        #pragma unroll
        for (int k = 0; k < 4; ++k) a[3][k] += fp82f((u3 >> (8 * k)) & 0xff);
        #pragma unroll
        for (int k = 0; k < 4; ++k) a[0][k] += fp82f((u4 >> (8 * k)) & 0xff);
        #pragma unroll
        for (int k = 0; k < 4; ++k) a[1][k] += fp82f((u5 >> (8 * k)) & 0xff);
        #pragma unroll
        for (int k = 0; k < 4; ++k) a[2][k] += fp82f((u6 >> (8 * k)) & 0xff);
        #pragma unroll
        for (int k = 0; k < 4; ++k) a[3][k] += fp82f((u7 >> (8 * k)) & 0xff);
    }
    for (int e = beg + n8; e < end; ++e) {
        int s = csr[e];
        unsigned u = *reinterpret_cast<const unsigned*>(feat + (size_t)s * 256 + c);
        #pragma unroll
        for (int k = 0; k < 4; ++k) a[0][k] += fp82f((u >> (8 * k)) & 0xff);
    }
    float inv = invdeg[node];
    uchar4 o;
    o.x = f2fp8((a[0][0] + a[1][0] + a[2][0] + a[3][0]) * inv);
    o.y = f2fp8((a[0][1] + a[1][1] + a[2][1] + a[3][1]) * inv);
    o.z = f2fp8((a[0][2] + a[1][2] + a[2][2] + a[3][2]) * inv);
    o.w = f2fp8((a[0][3] + a[1][3] + a[2][3] + a[3][3]) * inv);
    *reinterpret_cast<uchar4*>(&outp[(size_t)node * 256 + c]) = o;
}

// -------------------- fused GEMM + bias + leaky (all-fp8 operands) ---------
// C[M][256] = leaky( [AL | AR][M][512] @ B[512][256] + bias )
// Persistent 512 blocks, 1024 thr = 16 waves; wave w owns cols [w*16,+16).
// breg[16] = wave's B col-slice (K=512). 32-row tiles, split dbuf LDS
// ldsAL/ldsAR [2][32][256] (64KB). BOTH halves fp8 reg-staged: uint2 load ->
// exact fp8->bf16 dequant -> swizzled ds_write_b128. No global_load_lds.
// Pipeline (proven single-barrier flow): STAGE(next){2 uint2} -> MFMA(cur)
// -> vmcnt(0) -> WRITE(next, both halves) -> epilogue stores -> lgkmcnt(0)
// -> s_barrier. Swizzle: LDS_X[r][j] = X[r][j ^ ((r&15)<<3)] per half.
// C/D: lane l, reg r -> row (l>>4)*4+r, col l&15. OOB rows clamp to M-1.
template <int OUT_MODE>   // 0: fp8 h0q out, 1: f32 d_out
__global__ __launch_bounds__(1024, 4) void gemm_kernel(
    const unsigned char* __restrict__ ALq, const unsigned char* __restrict__ ARq,
    const short* __restrict__ BT, const float* __restrict__ bias,
    float* __restrict__ Cout, unsigned char* __restrict__ Cq,
    int M, int ntiles) {
    __shared__ short ldsAL[2][32 * 256];
    __shared__ short ldsAR[2][32 * 256];
    int wave = threadIdx.x >> 6;        // 0..15
    int lane = threadIdx.x & 63;
    int l16 = lane & 15;
    int lhi = lane >> 4;
    int c0 = wave * 16;
    int rsub = lane >> 5;               // 0/1: which of the wave's 2 rows
    int jcol = (lane & 31) * 8;         // element column within row

    bf16x8 breg[16];
    #pragma unroll
    for (int kk = 0; kk < 16; ++kk)
        breg[kk] = *reinterpret_cast<const bf16x8*>(
            &BT[(size_t)(c0 + l16) * 512 + kk * 32 + lhi * 8]);
    float bc = bias[c0 + l16];

    uint2 nqL, nqR;                     // staged fp8 row fragments

    auto STAGE = [&](int tt) {
        int r = 2 * wave + rsub;
        int grow = tt * 32 + r;
        if (grow >= M) grow = M - 1;
        int off = jcol ^ ((r & 15) << 3);
        nqL = *reinterpret_cast<const uint2*>(ALq + (size_t)grow * 256 + off);
        nqR = *reinterpret_cast<const uint2*>(ARq + (size_t)grow * 256 + off);
    };
    auto WRITE = [&](int buf) {         // dequant + swizzled LDS writes
        int r = 2 * wave + rsub;
        bf16x8 wl, wr;
        #pragma unroll
        for (int k = 0; k < 4; ++k) {
            wl[k]     = f2bf(fp82f((nqL.x >> (8 * k)) & 0xff));
            wl[4 + k] = f2bf(fp82f((nqL.y >> (8 * k)) & 0xff));
            wr[k]     = f2bf(fp82f((nqR.x >> (8 * k)) & 0xff));
            wr[4 + k] = f2bf(fp82f((nqR.y >> (8 * k)) & 0xff));
        }
        *reinterpret_cast<bf16x8*>(&ldsAL[buf][r * 256 + jcol]) = wl;
        *reinterpret_cast<bf16x8*>(&ldsAR[buf][r * 256 + jcol]) = wr;
    };

    int t = blockIdx.x;
    int stride = gridDim.x;
    if (t >= ntiles) return;

    // prologue: fill buffer 0 (also drains breg loads)
    STAGE(t);
    asm volatile("s_waitcnt vmcnt(0)" ::: "memory");
    WRITE(0);
    asm volatile("s_waitcnt lgkmcnt(0)" ::: "memory");
    __builtin_amdgcn_s_barrier();
    __builtin_amdgcn_sched_barrier(0);

    int buf = 0;
    for (; t < ntiles; t += stride) {
        int tn = t + stride;
        bool havenext = (tn < ntiles);
        if (havenext) STAGE(tn);            // loads fly under this tile

        int row0 = t * 32;
        f32x4 acc[2];
        acc[0] = (f32x4){0.f, 0.f, 0.f, 0.f};
        acc[1] = (f32x4){0.f, 0.f, 0.f, 0.f};

        #pragma unroll
        for (int kk = 0; kk < 16; ++kk) {
            const short* lb = (kk < 8) ? &ldsAL[buf][0] : &ldsAR[buf][0];
            int kb = (kk & 7) * 32 + lhi * 8;
            int swz0 = (l16 & 15) << 3;     // same for row l16 and 16+l16
            bf16x8 a0 = *reinterpret_cast<const bf16x8*>(
                &lb[l16 * 256 + (kb ^ swz0)]);
            bf16x8 a1 = *reinterpret_cast<const bf16x8*>(
                &lb[(16 + l16) * 256 + (kb ^ swz0)]);
            acc[0] = __builtin_amdgcn_mfma_f32_16x16x32_bf16(
                a0, breg[kk], acc[0], 0, 0, 0);
            acc[1] = __builtin_amdgcn_mfma_f32_16x16x32_bf16(
                a1, breg[kk], acc[1], 0, 0, 0);
        }

        // nq(next) in regs, prev stores done -- covered by MFMA phase.
        asm volatile("s_waitcnt vmcnt(0)" ::: "memory");
        if (havenext) WRITE(buf ^ 1);

        #pragma unroll
        for (int mt = 0; mt < 2; ++mt) {
            #pragma unroll
            for (int r = 0; r < 4; ++r) {
                int grow = row0 + mt * 16 + lhi * 4 + r;
                if (grow >= M) grow = M - 1;   // clamp (value-correct)
                int gcol = c0 + l16;
                float v = acc[mt][r] + bc;
                v = (v >= 0.f) ? v : 0.5f * v;
                if (OUT_MODE == 0) {
                    Cq[(size_t)grow * 256 + gcol] = f2fp8(v);
                } else {
                    Cout[(size_t)grow * 256 + gcol] = v;
                }
            }
        }
        asm volatile("s_waitcnt lgkmcnt(0)" ::: "memory");
        __builtin_amdgcn_s_barrier();
        __builtin_amdgcn_sched_barrier(0);
        buf ^= 1;
    }
}

// -------------------- launch --------------------

extern "C" void kernel_launch(void* const* d_in, const int* in_sizes, int n_in,
                              void* d_out, int out_size, void* d_ws, size_t ws_size,
                              hipStream_t stream) {
    const float* x   = (const float*)d_in[0];
    const int*   ei  = (const int*)d_in[1];   // int64 in ref -> int32 from harness
    const float* Wl0 = (const float*)d_in[2];
    const float* bl0 = (const float*)d_in[3];
    const float* Wr0 = (const float*)d_in[4];
    const float* Wl1 = (const float*)d_in[5];
    const float* bl1 = (const float*)d_in[6];
    const float* Wr1 = (const float*)d_in[7];

    const int N = in_sizes[0] / 256;
    const int E = in_sizes[1] / 2;
    const int NBK = (N + 127) / 128;               // <= 512
    int CH = 8192;
    while ((E + CH - 1) / CH > 128) CH <<= 1;      // NCH <= 128
    const int NCH = (E + CH - 1) / CH;
    int CAP = 1;
    while (CAP < 4 * (E / NBK + 1)) CAP <<= 1;     // bucket capacity, pow2

    char* ws = (char*)d_ws;
    size_t o = 0;
    auto alloc = [&](size_t bytes) {
        size_t p = o;
        o = (o + bytes + 255) & ~(size_t)255;
        return p;
    };
    int*   offs   = (int*)  (ws + alloc((size_t)N * 4));
    int*   oendv  = (int*)  (ws + alloc((size_t)N * 4));
    float* invdeg = (float*)(ws + alloc((size_t)N * 4));
    int*   histT  = (int*)  (ws + alloc((size_t)512 * 128 * 4));
    int*   bktot  = (int*)  (ws + alloc(512 * 4));
    unsigned* pairs = (unsigned*)(ws + alloc((size_t)NBK * CAP * 4));
    int*   csr    = (int*)  (ws + alloc((size_t)NBK * CAP * 4));
    unsigned char* meanb = (unsigned char*)(ws + alloc((size_t)N * 256));
    unsigned char* xq    = (unsigned char*)(ws + alloc((size_t)N * 256));
    unsigned char* h0q   = (unsigned char*)(ws + alloc((size_t)N * 256));
    short* B1T    = (short*)(ws + alloc(262144));
    short* B2T    = (short*)(ws + alloc(262144));

    int total8 = N * 32;
    int prep_blocks = (total8 + 262144 + 511) / 512;
    bkhist_prep_kernel<<<NCH + prep_blocks, 512, 0, stream>>>(
        ei, histT, E, NBK, NCH, CH,
        x, xq, (float*)d_out + (size_t)N * 256,
        Wl0, Wr0, Wl1, Wr1, B1T, B2T, total8);
    scanA_kernel<<<(NBK + 3) / 4, 256, 0, stream>>>(histT, bktot, NBK, NCH);
    binA_kernel<<<NCH, 512, 0, stream>>>(ei, histT, pairs, E, NBK, CH, CAP);
    binB_kernel<<<NBK, 256, 0, stream>>>(pairs, bktot, offs, oendv, invdeg,
                                         csr, NBK, N, CAP);

    int ab = (N + 3) / 4;
    int ntiles = (N + 31) / 32;
    int gblocks = 512;
    // layer 0
    agg_kernel<<<ab, 256, 0, stream>>>(xq, offs, oendv, csr, invdeg, meanb, N);
    gemm_kernel<0><<<gblocks, 1024, 0, stream>>>(
        meanb, xq, B1T, bl0, nullptr, h0q, N, ntiles);
    // layer 1
    agg_kernel<<<ab, 256, 0, stream>>>(h0q, offs, oendv, csr, invdeg, meanb, N);
    gemm_kernel<1><<<gblocks, 1024, 0, stream>>>(
        meanb, h0q, B2T, bl1, (float*)d_out, nullptr, N, ntiles);
}